// Round 1
// baseline (509.778 us; speedup 1.0000x reference)
//
#include <hip/hip_runtime.h>

#define HH 4
#define CC 128
#define NEG_SLOPE 0.2f
#define NPB 8

// ---------------- kernel 0: mean of edge_attr ----------------
__global__ void mean_reduce_kernel(const float* __restrict__ ea,
                                   float* __restrict__ out, int E) {
    float s = 0.f;
    for (int i = blockIdx.x * blockDim.x + threadIdx.x; i < E;
         i += gridDim.x * blockDim.x)
        s += ea[i];
    #pragma unroll
    for (int off = 32; off > 0; off >>= 1) s += __shfl_down(s, off, 64);
    __shared__ float wsum[4];
    int lane = threadIdx.x & 63, wid = threadIdx.x >> 6;
    if (lane == 0) wsum[wid] = s;
    __syncthreads();
    if (threadIdx.x == 0) {
        float t = 0.f;
        for (int w = 0; w < (int)(blockDim.x >> 6); ++w) t += wsum[w];
        atomicAdd(out, t);
    }
}

// ---------------- kernel A: per-edge logits + scalar aggregation ------------
// S layout: S[((comp*2 + b)*HH + h)*N + n], comp in {0:p*x0, 1:p*x1, 2:p}
__global__ __launch_bounds__(256) void edge_kernel(
    const float* __restrict__ x,
    const int* __restrict__ ei,
    const float* __restrict__ eattr,
    const float* __restrict__ meansum,
    const float* __restrict__ Wsrc0, const float* __restrict__ bsrc0,
    const float* __restrict__ Wdst0, const float* __restrict__ bdst0,
    const float* __restrict__ Wedge0, const float* __restrict__ att0,
    const float* __restrict__ Wsrc1, const float* __restrict__ bsrc1,
    const float* __restrict__ Wdst1, const float* __restrict__ bdst1,
    const float* __restrict__ Wedge1, const float* __restrict__ att1,
    float* __restrict__ S, int N, int E)
{
    int e = blockIdx.x * 256 + threadIdx.x;
    int Etot = E + N;
    if (e >= Etot) return;

    int src, dst;
    float ea;
    if (e < E) {
        src = ei[e];
        dst = ei[E + e];
        ea = eattr[e];
    } else {
        src = e - E;
        dst = src;
        ea = meansum[0] / (float)E;
    }
    float xs0 = x[2 * src], xs1 = x[2 * src + 1];
    float xd0 = x[2 * dst], xd1 = x[2 * dst + 1];

    float lg[2][HH];
    #pragma unroll
    for (int b = 0; b < 2; ++b)
        #pragma unroll
        for (int h = 0; h < HH; ++h) lg[b][h] = 0.f;

    #pragma unroll 4
    for (int c = 0; c < CC; ++c) {
        #pragma unroll
        for (int h = 0; h < HH; ++h) {
            int hc = h * CC + c;
            {
                float s = fmaf(xs0, Wsrc0[hc],
                          fmaf(xs1, Wsrc0[512 + hc],
                          fmaf(xd0, Wdst0[hc],
                          fmaf(xd1, Wdst0[512 + hc],
                          fmaf(ea, Wedge0[hc], bsrc0[hc] + bdst0[hc])))));
                s = (s > 0.f) ? s : NEG_SLOPE * s;
                lg[0][h] = fmaf(s, att0[hc], lg[0][h]);
            }
            {
                float s = fmaf(xs0, Wsrc1[hc],
                          fmaf(xs1, Wsrc1[512 + hc],
                          fmaf(xd0, Wdst1[hc],
                          fmaf(xd1, Wdst1[512 + hc],
                          fmaf(ea, Wedge1[hc], bsrc1[hc] + bdst1[hc])))));
                s = (s > 0.f) ? s : NEG_SLOPE * s;
                lg[1][h] = fmaf(s, att1[hc], lg[1][h]);
            }
        }
    }

    #pragma unroll
    for (int b = 0; b < 2; ++b) {
        #pragma unroll
        for (int h = 0; h < HH; ++h) {
            float p = __expf(lg[b][h]);
            atomicAdd(&S[((0 * 2 + b) * HH + h) * N + dst], p * xs0);
            atomicAdd(&S[((1 * 2 + b) * HH + h) * N + dst], p * xs1);
            atomicAdd(&S[((2 * 2 + b) * HH + h) * N + dst], p);
        }
    }
}

// ---------------- kernel B: per-node reconstruction + fuse matvec -----------
__global__ __launch_bounds__(256) void node_kernel(
    const float* __restrict__ x,
    const float* __restrict__ S,
    const float* __restrict__ Wsrc0, const float* __restrict__ bsrc0,
    const float* __restrict__ bias0, const float* __restrict__ Wres0,
    const float* __restrict__ Wsrc1, const float* __restrict__ bsrc1,
    const float* __restrict__ bias1, const float* __restrict__ Wres1,
    const float* __restrict__ Wfuse, const float* __restrict__ bfuse,
    float* __restrict__ out, int N)
{
    __shared__ __align__(16) float hbuf[NPB][2 * CC];
    int t = threadIdx.x;
    int c = t & (CC - 1);
    int half = t >> 7;  // 0 or 1
    int n0 = blockIdx.x * NPB;

    // per-channel weights (independent of node)
    float w00[HH], w01[HH], wb0[HH], w10[HH], w11[HH], wb1[HH];
    #pragma unroll
    for (int h = 0; h < HH; ++h) {
        w00[h] = Wsrc0[h * CC + c];
        w01[h] = Wsrc0[512 + h * CC + c];
        wb0[h] = bsrc0[h * CC + c];
        w10[h] = Wsrc1[h * CC + c];
        w11[h] = Wsrc1[512 + h * CC + c];
        wb1[h] = bsrc1[h * CC + c];
    }
    float bi0 = bias0[c], bi1 = bias1[c];
    float r00 = Wres0[c], r01 = Wres0[CC + c];
    float r10 = Wres1[c], r11 = Wres1[CC + c];

    // phase 1: build h0/h1 for NPB nodes
    for (int ni = half; ni < NPB; ni += 2) {
        int n = n0 + ni;
        if (n < N) {
            float x0 = x[2 * n], x1 = x[2 * n + 1];
            float h0v, h1v;
            {
                float acc = 0.f;
                #pragma unroll
                for (int h = 0; h < HH; ++h) {
                    float s0 = S[((0 * 2 + 0) * HH + h) * N + n];
                    float s1 = S[((1 * 2 + 0) * HH + h) * N + n];
                    float sb = S[((2 * 2 + 0) * HH + h) * N + n];
                    float num = fmaf(w00[h], s0, fmaf(w01[h], s1, wb0[h] * sb));
                    acc += num / (sb + 1e-16f);
                }
                float o = fmaxf(acc * 0.25f + bi0, 0.f);
                h0v = o + x0 * r00 + x1 * r01;
            }
            {
                float acc = 0.f;
                #pragma unroll
                for (int h = 0; h < HH; ++h) {
                    float s0 = S[((0 * 2 + 1) * HH + h) * N + n];
                    float s1 = S[((1 * 2 + 1) * HH + h) * N + n];
                    float sb = S[((2 * 2 + 1) * HH + h) * N + n];
                    float num = fmaf(w10[h], s0, fmaf(w11[h], s1, wb1[h] * sb));
                    acc += num / (sb + 1e-16f);
                }
                float o = fmaxf(acc * 0.25f + bi1, 0.f);
                h1v = o + x0 * r10 + x1 * r11;
            }
            hbuf[ni][c] = h0v;
            hbuf[ni][CC + c] = h1v;
        }
    }
    __syncthreads();

    // phase 2: fuse matvec, each thread handles 4 nodes at channel c
    float acc[4];
    float bf = bfuse[c];
    #pragma unroll
    for (int j = 0; j < 4; ++j) acc[j] = bf;

    for (int i = 0; i < 2 * CC; i += 4) {
        float wv0 = Wfuse[(i + 0) * CC + c];
        float wv1 = Wfuse[(i + 1) * CC + c];
        float wv2 = Wfuse[(i + 2) * CC + c];
        float wv3 = Wfuse[(i + 3) * CC + c];
        #pragma unroll
        for (int j = 0; j < 4; ++j) {
            int ni = half * 4 + j;
            float4 hv = *reinterpret_cast<const float4*>(&hbuf[ni][i]);
            acc[j] = fmaf(hv.x, wv0, fmaf(hv.y, wv1,
                     fmaf(hv.z, wv2, fmaf(hv.w, wv3, acc[j]))));
        }
    }
    #pragma unroll
    for (int j = 0; j < 4; ++j) {
        int n = n0 + half * 4 + j;
        if (n < N) out[n * CC + c] = fmaxf(acc[j], 0.f);
    }
}

extern "C" void kernel_launch(void* const* d_in, const int* in_sizes, int n_in,
                              void* d_out, int out_size, void* d_ws, size_t ws_size,
                              hipStream_t stream) {
    const float* x      = (const float*)d_in[0];
    const int*   ei     = (const int*)d_in[1];
    const float* eattr  = (const float*)d_in[2];
    const float* Wsrc0  = (const float*)d_in[3];
    const float* bsrc0  = (const float*)d_in[4];
    const float* Wdst0  = (const float*)d_in[5];
    const float* bdst0  = (const float*)d_in[6];
    const float* Wedge0 = (const float*)d_in[7];
    const float* att0   = (const float*)d_in[8];
    const float* bias0  = (const float*)d_in[9];
    const float* Wres0  = (const float*)d_in[10];
    const float* Wsrc1  = (const float*)d_in[11];
    const float* bsrc1  = (const float*)d_in[12];
    const float* Wdst1  = (const float*)d_in[13];
    const float* bdst1  = (const float*)d_in[14];
    const float* Wedge1 = (const float*)d_in[15];
    const float* att1   = (const float*)d_in[16];
    const float* bias1  = (const float*)d_in[17];
    const float* Wres1  = (const float*)d_in[18];
    const float* Wfuse  = (const float*)d_in[19];
    const float* bfuse  = (const float*)d_in[20];
    float* out = (float*)d_out;

    int N = in_sizes[0] / 2;   // x is (N,2)
    int E = in_sizes[1] / 2;   // edge_index is (2,E)

    float* meansum = (float*)d_ws;
    float* S = (float*)((char*)d_ws + 256);
    size_t zbytes = 256 + (size_t)24 * N * sizeof(float);
    hipMemsetAsync(d_ws, 0, zbytes, stream);

    mean_reduce_kernel<<<64, 256, 0, stream>>>(eattr, meansum, E);

    int Etot = E + N;
    edge_kernel<<<(Etot + 255) / 256, 256, 0, stream>>>(
        x, ei, eattr, meansum,
        Wsrc0, bsrc0, Wdst0, bdst0, Wedge0, att0,
        Wsrc1, bsrc1, Wdst1, bdst1, Wedge1, att1,
        S, N, E);

    node_kernel<<<(N + NPB - 1) / NPB, 256, 0, stream>>>(
        x, S,
        Wsrc0, bsrc0, bias0, Wres0,
        Wsrc1, bsrc1, bias1, Wres1,
        Wfuse, bfuse, out, N);
}